// Round 1
// baseline (70.765 us; speedup 1.0000x reference)
//
#include <hip/hip_runtime.h>

// Chamfer via MFMA — R13: occupancy fix on top of the R9 structure.
// d2 = psq + qsq - 2 p.q in ONE v_mfma_f32_32x32x16_bf16 per 32x32 tile
// (packing PROVEN R6-R12, absmax 0.0):
//   A k: {psqh,psql,-2ph(y,z,w),-2pl(y,z,w) | -2ph(y,z,w),1,1,0,0,0}
//   B k: {1,1,qh(y,z,w),qh(y,z,w) | ql(y,z,w),qsqh,qsql,0,0,0}
// R13 change: LDS trimmed to EXACTLY 40960 B (wsum removed; per-wave
// partials go straight to ws as part[blk*4+wv]) + __launch_bounds__(256,4)
// -> 4 blocks/CU co-resident (grid is exactly 4 blocks/CU), killing the
// 4-blocks-into-3-slots straggler generation of the R9 kernel.
// Final kernel folds the 4 wave-partials per block in the SAME
// left-to-right order as the old wsum[0]+wsum[1]+wsum[2]+wsum[3], so the
// output is bitwise identical (absmax 0.0 preserved).
// Grid: 128 batches x 2 dirs x 4 col-blocks = 1024 blocks x 256 thr
// (4 waves x 2 col-tiles each). Non-atomic partials -> ws; 1-block final
// kernel sums them (per-block atomicAdd REGRESSES: same-address herd,
// +7 µs measured in R12).

typedef short bf16x8 __attribute__((ext_vector_type(8)));
typedef float f32x16 __attribute__((ext_vector_type(16)));

#define ONE_BF 0x3f80

__device__ __forceinline__ unsigned short f2bf(float x) {
    unsigned u = __float_as_uint(x);
    u += 0x7fffu + ((u >> 16) & 1u);          // round-to-nearest-even
    return (unsigned short)(u >> 16);
}
__device__ __forceinline__ float bf2f(unsigned short h) {
    return __uint_as_float(((unsigned)h) << 16);
}

__global__ __launch_bounds__(256, 4) void chamfer_dir(
    const float4* __restrict__ P, const float4* __restrict__ Q,
    float* __restrict__ part)
{
    __shared__ short lAh[1024 * 8];   // A k-slots 0-7  (16 KB)
    __shared__ short lAl[1024 * 8];   // A k-slots 8-15 (16 KB)
    __shared__ short lB[256 * 16];    // B interleaved [pt][half][8] (8 KB)
    // total 40960 B exactly -> 4 blocks/CU (160 KiB/CU)

    const int blk   = blockIdx.x;
    const int batch = blk >> 3;        // 0..127
    const int dir   = (blk >> 2) & 1;  // 0: rows=P cols=Q; 1: swapped
    const int cb    = blk & 3;         // col-block (256 cols each)
    const int t     = threadIdx.x;
    const int base  = batch << 10;

    const float4* __restrict__ ownb = (dir ? Q : P) + base;   // rows
    const float4* __restrict__ oppb = (dir ? P : Q) + base;   // cols

    // ---- Pack rows (full cloud) into LDS A-fragments: 4 pts/thread ----
#pragma unroll
    for (int i = 0; i < 4; ++i) {
        const int pt = t + (i << 8);
        float4 v = ownb[pt];
        float psq = v.y * v.y + v.z * v.z + v.w * v.w;
        unsigned short psqh = f2bf(psq);
        unsigned short psql = f2bf(psq - bf2f(psqh));
        unsigned short yh = f2bf(v.y), zh = f2bf(v.z), wh = f2bf(v.w);
        unsigned short m2yh = f2bf(-2.0f * bf2f(yh));
        unsigned short m2zh = f2bf(-2.0f * bf2f(zh));
        unsigned short m2wh = f2bf(-2.0f * bf2f(wh));
        unsigned short m2yl = f2bf(-2.0f * (v.y - bf2f(yh)));
        unsigned short m2zl = f2bf(-2.0f * (v.z - bf2f(zh)));
        unsigned short m2wl = f2bf(-2.0f * (v.w - bf2f(wh)));
        bf16x8 ah = { (short)psqh, (short)psql, (short)m2yh, (short)m2zh,
                      (short)m2wh, (short)m2yl, (short)m2zl, (short)m2wl };
        bf16x8 al = { (short)m2yh, (short)m2zh, (short)m2wh,
                      (short)ONE_BF, (short)ONE_BF, 0, 0, 0 };
        *(bf16x8*)&lAh[pt * 8] = ah;
        *(bf16x8*)&lAl[pt * 8] = al;
    }
    // ---- Pack this block's 256 cols into LDS B-fragments ----
    {
        float4 v = oppb[(cb << 8) + t];
        float qsq = v.y * v.y + v.z * v.z + v.w * v.w;
        unsigned short qsqh = f2bf(qsq);
        unsigned short qsql = f2bf(qsq - bf2f(qsqh));
        unsigned short yh = f2bf(v.y), zh = f2bf(v.z), wh = f2bf(v.w);
        unsigned short yl = f2bf(v.y - bf2f(yh));
        unsigned short zl = f2bf(v.z - bf2f(zh));
        unsigned short wl = f2bf(v.w - bf2f(wh));
        bf16x8 bh = { (short)ONE_BF, (short)ONE_BF, (short)yh, (short)zh,
                      (short)wh, (short)yh, (short)zh, (short)wh };
        bf16x8 bl = { (short)yl, (short)zl, (short)wl,
                      (short)qsqh, (short)qsql, 0, 0, 0 };
        *(bf16x8*)&lB[t * 16]     = bh;
        *(bf16x8*)&lB[t * 16 + 8] = bl;
    }
    __syncthreads();

    const int lane = t & 63;
    const int half = lane >> 5;    // k-half: 0 -> slots 0-7, 1 -> 8-15
    const int l31  = lane & 31;
    const int wv   = t >> 6;

    const short* aptr = half ? lAl : lAh;

    // Two local col-tiles per wave: c0 = wv*2, c0+1
    const int c0 = wv << 1;
    bf16x8 bf0 = *(const bf16x8*)&lB[(((c0 << 5) + l31) * 2 + half) * 8];
    bf16x8 bf1 = *(const bf16x8*)&lB[((((c0 + 1) << 5) + l31) * 2 + half) * 8];

    f32x16 zf;
#pragma unroll
    for (int j = 0; j < 16; ++j) zf[j] = 0.0f;

    f32x16 acc0, acc1;
#pragma unroll
    for (int j = 0; j < 16; ++j) { acc0[j] = 3.4e38f; acc1[j] = 3.4e38f; }

    // Inner loop: 2 row-tiles/step, elementwise min3 fold, NO reductions.
    // Two named transients (not four) to keep VGPR <= 128 at 4 waves/EU.
    for (int rt = 0; rt < 32; rt += 2) {
        bf16x8 af0 = *(const bf16x8*)&aptr[((rt << 5) + l31) * 8];
        bf16x8 af1 = *(const bf16x8*)&aptr[(((rt + 1) << 5) + l31) * 8];
        f32x16 ca = __builtin_amdgcn_mfma_f32_32x32x16_bf16(af0, bf0, zf, 0, 0, 0);
        f32x16 cb = __builtin_amdgcn_mfma_f32_32x32x16_bf16(af1, bf0, zf, 0, 0, 0);
#pragma unroll
        for (int j = 0; j < 16; ++j)
            acc0[j] = fminf(fminf(ca[j], cb[j]), acc0[j]);   // v_min3_f32
        ca = __builtin_amdgcn_mfma_f32_32x32x16_bf16(af0, bf1, zf, 0, 0, 0);
        cb = __builtin_amdgcn_mfma_f32_32x32x16_bf16(af1, bf1, zf, 0, 0, 0);
#pragma unroll
        for (int j = 0; j < 16; ++j)
            acc1[j] = fminf(fminf(ca[j], cb[j]), acc1[j]);
    }

    // Epilogue: 16->1 tree, cross-half shfl, sqrt, wave-sum, wave partial.
    float m0 = acc0[0], m1 = acc1[0];
#pragma unroll
    for (int j = 1; j < 16; ++j) { m0 = fminf(m0, acc0[j]); m1 = fminf(m1, acc1[j]); }
    m0 = fminf(m0, __shfl_xor(m0, 32, 64));
    m1 = fminf(m1, __shfl_xor(m1, 32, 64));

    float s = 0.0f;
    if (half == 0)
        s = sqrtf(fmaxf(m0, 0.0f) + 1e-12f) + sqrtf(fmaxf(m1, 0.0f) + 1e-12f);
#pragma unroll
    for (int off = 32; off; off >>= 1) s += __shfl_down(s, off, 64);
    if (lane == 0) part[(blk << 2) + wv] = s;
}

__global__ __launch_bounds__(256) void chamfer_final(
    const float* __restrict__ part, float* __restrict__ out)
{
    __shared__ float ws[4];
    const int t = threadIdx.x;
    // Reproduce the R9 summation order EXACTLY:
    //   B(i) = ((w0+w1)+w2)+w3  per block i  (was the wsum[] add)
    //   s    = ((B(t)+B(t+256))+B(t+512))+B(t+768)
    float s = 0.0f;
#pragma unroll
    for (int k = 0; k < 4; ++k) {
        const float4 w = *(const float4*)&part[(t + (k << 8)) << 2];
        float bk = ((w.x + w.y) + w.z) + w.w;
        s = (k == 0) ? bk : (s + bk);
    }
#pragma unroll
    for (int off = 32; off; off >>= 1) s += __shfl_down(s, off, 64);
    if ((t & 63) == 0) ws[t >> 6] = s;
    __syncthreads();
    if (t == 0) out[0] = ws[0] + ws[1] + ws[2] + ws[3];
}

extern "C" void kernel_launch(void* const* d_in, const int* in_sizes, int n_in,
                              void* d_out, int out_size, void* d_ws, size_t ws_size,
                              hipStream_t stream) {
    const float4* P = (const float4*)d_in[0];
    const float4* Q = (const float4*)d_in[1];
    float* out  = (float*)d_out;
    float* part = (float*)d_ws;   // 4096 per-wave partials (16 KB)

    chamfer_dir<<<dim3(128 * 2 * 4), dim3(256), 0, stream>>>(P, Q, part);
    chamfer_final<<<dim3(1), dim3(256), 0, stream>>>(part, out);
}

// Round 2
// 66.558 us; speedup vs baseline: 1.0632x; 1.0632x over previous
//
#include <hip/hip_runtime.h>

// Chamfer via MFMA — R14: pack-once grid + fully-unrolled ILP loop.
// d2 = psq + qsq - 2 p.q in ONE v_mfma_f32_32x32x16_bf16 per 32x32 tile
// (packing PROVEN R6-R12, absmax 0.0):
//   A k: {psqh,psql,-2ph(y,z,w),-2pl(y,z,w) | -2ph(y,z,w),1,1,0,0,0}
//   B k: {1,1,qh(y,z,w),qh(y,z,w) | ql(y,z,w),qsqh,qsql,0,0,0}
// R14 changes vs R13 (R13 was NEUTRAL -> occupancy was not the lever):
//  1. Grid 256 blocks (batch x dir) x 1024 thr: rows+cols packed ONCE per
//     (batch,dir) instead of 4x (per col-block). HBM fetch 20 MB -> 8 MB,
//     pack conversions 1.3M -> 0.5M points. LDS 64 KB, 1 block/CU,
//     16 waves = 4/SIMD (same occupancy as R13, deterministic residency).
//  2. Main loop FULLY UNROLLED: SSA transients per iteration remove the
//     WAR serialization (R13 reused 2 transients -> 2nd MFMA pair blocked
//     on 1st pair's folds); ds_read_b128 gets immediate offsets.
//  3. Per-wave work + partial layout BITWISE IDENTICAL to R13: wave w of
//     block (batch,dir) == old wave (cb=w>>2, wv=w&3) of old block
//     (batch,dir,cb); part index batch*32+dir*16+w matches old slot.
//     Final kernel unchanged -> absmax 0.0 preserved.
// Non-atomic partials -> ws; 1-block final kernel sums them (atomicAdd
// herd REGRESSES +7 µs, R12).

typedef short bf16x8 __attribute__((ext_vector_type(8)));
typedef float f32x16 __attribute__((ext_vector_type(16)));

#define ONE_BF 0x3f80

__device__ __forceinline__ unsigned short f2bf(float x) {
    unsigned u = __float_as_uint(x);
    u += 0x7fffu + ((u >> 16) & 1u);          // round-to-nearest-even
    return (unsigned short)(u >> 16);
}
__device__ __forceinline__ float bf2f(unsigned short h) {
    return __uint_as_float(((unsigned)h) << 16);
}

__global__ __launch_bounds__(1024, 4) void chamfer_dir(
    const float4* __restrict__ P, const float4* __restrict__ Q,
    float* __restrict__ part)
{
    __shared__ short lAh[1024 * 8];   // A k-slots 0-7  (16 KB)
    __shared__ short lAl[1024 * 8];   // A k-slots 8-15 (16 KB)
    __shared__ short lB[1024 * 16];   // B interleaved [pt][half][8] (32 KB)
    // total 64 KB -> 1 block/CU with grid 256 = CU count

    const int blk   = blockIdx.x;      // 0..255
    const int batch = blk >> 1;        // 0..127
    const int dir   = blk & 1;         // 0: rows=P cols=Q; 1: swapped
    const int t     = threadIdx.x;     // 0..1023
    const int base  = batch << 10;

    const float4* __restrict__ ownb = (dir ? Q : P) + base;   // rows
    const float4* __restrict__ oppb = (dir ? P : Q) + base;   // cols

    // ---- Pack rows into LDS A-fragments: 1 pt/thread ----
    {
        float4 v = ownb[t];
        float psq = v.y * v.y + v.z * v.z + v.w * v.w;
        unsigned short psqh = f2bf(psq);
        unsigned short psql = f2bf(psq - bf2f(psqh));
        unsigned short yh = f2bf(v.y), zh = f2bf(v.z), wh = f2bf(v.w);
        unsigned short m2yh = f2bf(-2.0f * bf2f(yh));
        unsigned short m2zh = f2bf(-2.0f * bf2f(zh));
        unsigned short m2wh = f2bf(-2.0f * bf2f(wh));
        unsigned short m2yl = f2bf(-2.0f * (v.y - bf2f(yh)));
        unsigned short m2zl = f2bf(-2.0f * (v.z - bf2f(zh)));
        unsigned short m2wl = f2bf(-2.0f * (v.w - bf2f(wh)));
        bf16x8 ah = { (short)psqh, (short)psql, (short)m2yh, (short)m2zh,
                      (short)m2wh, (short)m2yl, (short)m2zl, (short)m2wl };
        bf16x8 al = { (short)m2yh, (short)m2zh, (short)m2wh,
                      (short)ONE_BF, (short)ONE_BF, 0, 0, 0 };
        *(bf16x8*)&lAh[t * 8] = ah;
        *(bf16x8*)&lAl[t * 8] = al;
    }
    // ---- Pack ALL 1024 cols into LDS B-fragments: 1 pt/thread ----
    {
        float4 v = oppb[t];
        float qsq = v.y * v.y + v.z * v.z + v.w * v.w;
        unsigned short qsqh = f2bf(qsq);
        unsigned short qsql = f2bf(qsq - bf2f(qsqh));
        unsigned short yh = f2bf(v.y), zh = f2bf(v.z), wh = f2bf(v.w);
        unsigned short yl = f2bf(v.y - bf2f(yh));
        unsigned short zl = f2bf(v.z - bf2f(zh));
        unsigned short wl = f2bf(v.w - bf2f(wh));
        bf16x8 bh = { (short)ONE_BF, (short)ONE_BF, (short)yh, (short)zh,
                      (short)wh, (short)yh, (short)zh, (short)wh };
        bf16x8 bl = { (short)yl, (short)zl, (short)wl,
                      (short)qsqh, (short)qsql, 0, 0, 0 };
        *(bf16x8*)&lB[t * 16]     = bh;
        *(bf16x8*)&lB[t * 16 + 8] = bl;
    }
    __syncthreads();

    const int lane = t & 63;
    const int half = lane >> 5;    // k-half: 0 -> slots 0-7, 1 -> 8-15
    const int l31  = lane & 31;
    const int wv   = t >> 6;       // 0..15

    const short* __restrict__ aptr = half ? lAl : lAh;

    // Two GLOBAL col-tiles per wave: c0 = wv*2, c0+1 (== old cb*8+2*wvold)
    const int c0 = wv << 1;
    bf16x8 bf0 = *(const bf16x8*)&lB[((((c0)     << 5) + l31) * 2 + half) * 8];
    bf16x8 bf1 = *(const bf16x8*)&lB[((((c0 + 1) << 5) + l31) * 2 + half) * 8];

    f32x16 zf;
#pragma unroll
    for (int j = 0; j < 16; ++j) zf[j] = 0.0f;

    f32x16 acc0, acc1;
#pragma unroll
    for (int j = 0; j < 16; ++j) { acc0[j] = 3.4e38f; acc1[j] = 3.4e38f; }

    // Fully-unrolled inner loop: 2 row-tiles/step, 4 independent MFMA
    // streams per step (SSA transients -> no WAR chain), elementwise min3
    // fold, NO cross-lane reductions inside the loop.
#pragma unroll
    for (int rt = 0; rt < 32; rt += 2) {
        bf16x8 af0 = *(const bf16x8*)&aptr[((rt << 5) + l31) * 8];
        bf16x8 af1 = *(const bf16x8*)&aptr[(((rt + 1) << 5) + l31) * 8];
        f32x16 ca = __builtin_amdgcn_mfma_f32_32x32x16_bf16(af0, bf0, zf, 0, 0, 0);
        f32x16 cb = __builtin_amdgcn_mfma_f32_32x32x16_bf16(af1, bf0, zf, 0, 0, 0);
        f32x16 cc = __builtin_amdgcn_mfma_f32_32x32x16_bf16(af0, bf1, zf, 0, 0, 0);
        f32x16 cd = __builtin_amdgcn_mfma_f32_32x32x16_bf16(af1, bf1, zf, 0, 0, 0);
#pragma unroll
        for (int j = 0; j < 16; ++j)
            acc0[j] = fminf(fminf(ca[j], cb[j]), acc0[j]);   // v_min3_f32
#pragma unroll
        for (int j = 0; j < 16; ++j)
            acc1[j] = fminf(fminf(cc[j], cd[j]), acc1[j]);
    }

    // Epilogue: 16->1 tree, cross-half shfl, sqrt, wave-sum, wave partial.
    // (identical arithmetic + order to R13 -> bitwise-same partials)
    float m0 = acc0[0], m1 = acc1[0];
#pragma unroll
    for (int j = 1; j < 16; ++j) { m0 = fminf(m0, acc0[j]); m1 = fminf(m1, acc1[j]); }
    m0 = fminf(m0, __shfl_xor(m0, 32, 64));
    m1 = fminf(m1, __shfl_xor(m1, 32, 64));

    float s = 0.0f;
    if (half == 0)
        s = sqrtf(fmaxf(m0, 0.0f) + 1e-12f) + sqrtf(fmaxf(m1, 0.0f) + 1e-12f);
#pragma unroll
    for (int off = 32; off; off >>= 1) s += __shfl_down(s, off, 64);
    if (lane == 0) part[(blk << 4) + wv] = s;   // == batch*32 + dir*16 + w
}

__global__ __launch_bounds__(256) void chamfer_final(
    const float* __restrict__ part, float* __restrict__ out)
{
    __shared__ float ws[4];
    const int t = threadIdx.x;
    // Same linear 4096-partial array + same summation order as R13.
    float s = 0.0f;
#pragma unroll
    for (int k = 0; k < 4; ++k) {
        const float4 w = *(const float4*)&part[(t + (k << 8)) << 2];
        float bk = ((w.x + w.y) + w.z) + w.w;
        s = (k == 0) ? bk : (s + bk);
    }
#pragma unroll
    for (int off = 32; off; off >>= 1) s += __shfl_down(s, off, 64);
    if ((t & 63) == 0) ws[t >> 6] = s;
    __syncthreads();
    if (t == 0) out[0] = ws[0] + ws[1] + ws[2] + ws[3];
}

extern "C" void kernel_launch(void* const* d_in, const int* in_sizes, int n_in,
                              void* d_out, int out_size, void* d_ws, size_t ws_size,
                              hipStream_t stream) {
    const float4* P = (const float4*)d_in[0];
    const float4* Q = (const float4*)d_in[1];
    float* out  = (float*)d_out;
    float* part = (float*)d_ws;   // 4096 per-wave partials (16 KB)

    chamfer_dir<<<dim3(128 * 2), dim3(1024), 0, stream>>>(P, Q, part);
    chamfer_final<<<dim3(1), dim3(256), 0, stream>>>(part, out);
}